// Round 13
// baseline (9900.314 us; speedup 1.0000x reference)
//
#include <hip/hip_runtime.h>

#define Tt  512
#define Hd  1024
#define Cc  10
#define THREADS 512
#define POLL_BOUND 20000
#define HBHALF (256 * 1024)   // elements per h buffer [256][1024]

typedef short bf16x8 __attribute__((ext_vector_type(8)));
typedef float f32x4 __attribute__((ext_vector_type(4)));
typedef unsigned u32x4 __attribute__((ext_vector_type(4)));

__device__ __forceinline__ unsigned short f2bf(float f) {
  unsigned u = __builtin_bit_cast(unsigned, f);
  u = (u + 0x7FFFu + ((u >> 16) & 1u)) >> 16;   // RTNE
  return (unsigned short)u;
}
__device__ __forceinline__ float bf2f(unsigned short s) {
  unsigned u = ((unsigned)s) << 16;
  return __builtin_bit_cast(float, u);
}
__device__ __forceinline__ float sigmf_(float z) { return 1.0f / (1.0f + __expf(-z)); }
__device__ __forceinline__ float tanhf_(float z) { return 1.0f - 2.0f / (__expf(2.0f * z) + 1.0f); }

__device__ __forceinline__ void store_u32_sc0(unsigned* p, unsigned v) {
  asm volatile("global_store_dword %0, %1, off sc0" :: "v"(p), "v"(v) : "memory");
}
// Atomic RMW executes at the XCD-local L2 — always fresh (v5/v7 proven, absmax 0.0).
__device__ __forceinline__ unsigned atomic_read_l2(unsigned* p) {
  unsigned old, zero = 0u;
  asm volatile("global_atomic_add %0, %1, %2, off sc0\n\ts_waitcnt vmcnt(0)"
               : "=&v"(old) : "v"(p), "v"(zero) : "memory");
  return old;
}

// ---- prep: fuse+transpose Wh (f32 [k][col]) -> whT (bf16 [gate][col][k]) ----
__global__ __launch_bounds__(256) void lstm_prep(
    const float* __restrict__ wgh, const float* __restrict__ wih,
    const float* __restrict__ wfh, const float* __restrict__ woh,
    unsigned short* __restrict__ whT)
{
  __shared__ float tile[64][65];
  const int bid = blockIdx.x;
  const int q  = bid >> 8;
  const int ct = (bid >> 4) & 15;
  const int kt = bid & 15;
  const float* w = (q == 0) ? wgh : (q == 1) ? wih : (q == 2) ? wfh : woh;
  const int tid = threadIdx.x;
  const int tc = tid & 63, tr = tid >> 6;
  #pragma unroll
  for (int i = 0; i < 16; ++i) {
    int kk = i * 4 + tr;
    tile[kk][tc] = w[(size_t)(kt * 64 + kk) * Hd + ct * 64 + tc];
  }
  __syncthreads();
  #pragma unroll
  for (int i = 0; i < 16; ++i) {
    int cc = i * 4 + tr;
    whT[(size_t)(q * 1024 + ct * 64 + cc) * Hd + kt * 64 + tc] = f2bf(tile[tc][cc]);
  }
}

// ---- two timesteps per dispatch; XCD-local producer flags between them ----
// 83.2KB LDS forces 1 block/CU -> exactly 32 blocks/XCD (capacity argument),
// so the per-XCD flag protocol is correct by construction under a plain launch.
__global__ void lstm_pair(
    const unsigned short* __restrict__ whT,
    const float* __restrict__ x,
    const float* __restrict__ wgx, const float* __restrict__ wix,
    const float* __restrict__ wfx, const float* __restrict__ wox,
    const float* __restrict__ bg,  const float* __restrict__ bi,
    const float* __restrict__ bfp, const float* __restrict__ bo,
    unsigned short* __restrict__ hbuf,   // [2][256][1024] bf16
    float* __restrict__ cbuf,            // [256][1024] f32
    unsigned* __restrict__ sync,         // flags[8][32] lines | cnt[8]
    int k)                               // dispatch index (t = 2k, 2k+1)
{
  extern __shared__ char smem[];
  char*  hls  = smem;                               // [32 rows][2048B] swizzled, 64KB
  float* zbuf = (float*)(smem + 65536);             // [32][128] f32, 16KB
  float* xsh  = (float*)(smem + 65536 + 16384);     // [2][32]
  float* wxb  = xsh + 64;                           // [4][32]
  float* bbl  = wxb + 128;                          // [4][32]

  __shared__ int slot_sh;

  const int tid = threadIdx.x;
  const int l   = tid & 63;
  const int w   = tid >> 6;          // wave 0..7

  unsigned xcd_r;
  asm("s_getreg_b32 %0, hwreg(HW_REG_XCC_ID, 0, 4)" : "=s"(xcd_r));
  const int g  = (int)(xcd_r & 7);
  const int r0 = g * 32;

  const unsigned short* hR = hbuf;            // h_2k   (parity 0)
  unsigned short*       hM = hbuf + HBHALF;   // h_2k+1 (parity 1)
  unsigned short*       hW = hbuf;            // h_2k+2 (parity 0)

  // ---- issue step-A staging immediately (needs only g) ----
  {
    int rbase = w * 4;
    #pragma unroll
    for (int i = 0; i < 8; ++i) {
      int r = rbase + (i >> 1);
      int half = i & 1;
      char* ldsb = hls + r * 2048 + half * 1024;   // wave-uniform, linear dest
      int m = half * 64 + l;
      int srcc = m ^ (r & 7);                       // inverse swizzle on source
      const char* gp = (const char*)hR + (((size_t)(r0 + r) << 10) + srcc * 8) * 2;
      __builtin_amdgcn_global_load_lds(gp, ldsb, 16, 0, 0);
    }
  }

  // ---- claim col-slot on this XCD ----
  unsigned* gflag = sync + g * (32 * 32);
  unsigned* cntp  = sync + 8 * 32 * 32;
  if (tid == 0) {
    unsigned s = __hip_atomic_fetch_add(&cntp[g], 1u, __ATOMIC_RELAXED,
                                        __HIP_MEMORY_SCOPE_AGENT);
    slot_sh = (int)(s & 31u);
  }
  __syncthreads();                    // staging landed + slot visible
  const int j   = slot_sh;
  const int hc0 = j * 32;

  // ---- per-dispatch init: wx/b -> LDS, x cols 2k/2k+1 -> LDS, c reload ----
  if (tid < 128) {
    int qq = tid >> 5, hcl = tid & 31;
    const float* px = (qq == 0) ? wgx : (qq == 1) ? wix : (qq == 2) ? wfx : wox;
    const float* pb = (qq == 0) ? bg  : (qq == 1) ? bi  : (qq == 2) ? bfp : bo;
    wxb[tid] = px[hc0 + hcl];
    bbl[tid] = pb[hc0 + hcl];
  }
  if (tid < 64) xsh[tid] = x[(size_t)(r0 + (tid & 31)) * Tt + 2 * k + (tid >> 5)];

  const int r_a = tid >> 5,        hc_a = tid & 31;
  const int r_b = (tid + 512) >> 5, hc_b = tid & 31;
  const size_t ci_a = (size_t)(r0 + r_a) * Hd + hc0 + hc_a;
  const size_t ci_b = (size_t)(r0 + r_b) * Hd + hc0 + hc_b;
  float creg0 = cbuf[ci_a];
  float creg1 = cbuf[ci_b];

  const int q  = w >> 1;
  const int lc = l & 15;
  const int roff0 = lc * 2048;
  const int roff1 = roff0 + 16 * 2048;
  const int swz   = (l & 7) << 4;
  const int kboff = (l >> 4) * 16;
  const unsigned short* wcol =
      whT + (size_t)(q * 1024 + hc0 + ((w & 1) << 4) + lc) * Hd + (l >> 4) * 8;
  const unsigned tk = (unsigned)(k + 1);

  // ================= STEP A (t = 2k) =================
  {
    f32x4 acc0 = {0.f,0.f,0.f,0.f};
    f32x4 acc1 = {0.f,0.f,0.f,0.f};
    #pragma unroll
    for (int kc = 0; kc < 32; ++kc) {
      int boff = (kc * 64 + kboff) ^ swz;
      bf16x8 a0 = *(const bf16x8*)(hls + roff0 + boff);
      bf16x8 a1 = *(const bf16x8*)(hls + roff1 + boff);
      bf16x8 b  = *(const bf16x8*)(wcol + kc * 32);
      acc0 = __builtin_amdgcn_mfma_f32_16x16x32_bf16(a0, b, acc0, 0, 0, 0);
      acc1 = __builtin_amdgcn_mfma_f32_16x16x32_bf16(a1, b, acc1, 0, 0, 0);
    }
    int colz  = (w << 4) + lc;
    int rbase = (l >> 4) * 4;
    #pragma unroll
    for (int p = 0; p < 4; ++p) {
      zbuf[(rbase + p) * 128 + colz]      = acc0[p];
      zbuf[(rbase + p + 16) * 128 + colz] = acc1[p];
    }
  }
  __syncthreads();

  #pragma unroll
  for (int e = 0; e < 2; ++e) {
    int idx = tid + e * 512;
    int r = idx >> 5, hc = idx & 31;
    float xv = xsh[r];
    float zg = zbuf[r * 128 +       hc] + xv * wxb[      hc] + bbl[      hc];
    float zi = zbuf[r * 128 +  32 + hc] + xv * wxb[ 32 + hc] + bbl[ 32 + hc];
    float zf = zbuf[r * 128 +  64 + hc] + xv * wxb[ 64 + hc] + bbl[ 64 + hc];
    float zo = zbuf[r * 128 +  96 + hc] + xv * wxb[ 96 + hc] + bbl[ 96 + hc];
    float G = tanhf_(zg), I = sigmf_(zi), F = sigmf_(zf), O = sigmf_(zo);
    float cold = e ? creg1 : creg0;
    float cnew = G * I + cold * F;
    if (e) creg1 = cnew; else creg0 = cnew;
    hM[(size_t)(r0 + r) * Hd + hc0 + hc] = f2bf(tanhf_(cnew) * O);
  }

  // ---- publish: flag slot j (stores drained by barrier) ----
  __syncthreads();
  if (tid == 0) store_u32_sc0(&gflag[j * 32], tk);

  // ================= STEP B (t = 2k+1) =================
  // wave w consumes producers 4w..4w+3 only: poll 4 flags, stage their 8KB.
  {
    unsigned v = 0xFFFFFFFFu;
    unsigned* fp = &gflag[(4 * w + (l & 3)) * 32];
    int it = 0;
    while (1) {
      if (l < 4) v = atomic_read_l2(fp);
      if (__all((int)(v >= tk))) break;
      if (++it >= POLL_BOUND) break;          // fail fast -> absmax catches
      __builtin_amdgcn_s_sleep(1);
    }
    #pragma unroll
    for (int i = 0; i < 8; ++i) {
      int row = i * 4 + (l >> 4);
      int m   = 16 * w + (l & 15);
      u32x4 v4 = *(const u32x4*)((const char*)hM +
                   ((size_t)(r0 + row) << 11) + m * 16);
      *(u32x4*)(hls + row * 2048 + ((m * 16) ^ ((row & 7) << 4))) = v4;
    }
  }
  __syncthreads();

  {
    f32x4 acc0 = {0.f,0.f,0.f,0.f};
    f32x4 acc1 = {0.f,0.f,0.f,0.f};
    #pragma unroll
    for (int kc = 0; kc < 32; ++kc) {
      int boff = (kc * 64 + kboff) ^ swz;
      bf16x8 a0 = *(const bf16x8*)(hls + roff0 + boff);
      bf16x8 a1 = *(const bf16x8*)(hls + roff1 + boff);
      bf16x8 b  = *(const bf16x8*)(wcol + kc * 32);
      acc0 = __builtin_amdgcn_mfma_f32_16x16x32_bf16(a0, b, acc0, 0, 0, 0);
      acc1 = __builtin_amdgcn_mfma_f32_16x16x32_bf16(a1, b, acc1, 0, 0, 0);
    }
    int colz  = (w << 4) + lc;
    int rbase = (l >> 4) * 4;
    #pragma unroll
    for (int p = 0; p < 4; ++p) {
      zbuf[(rbase + p) * 128 + colz]      = acc0[p];
      zbuf[(rbase + p + 16) * 128 + colz] = acc1[p];
    }
  }
  __syncthreads();

  #pragma unroll
  for (int e = 0; e < 2; ++e) {
    int idx = tid + e * 512;
    int r = idx >> 5, hc = idx & 31;
    float xv = xsh[32 + r];
    float zg = zbuf[r * 128 +       hc] + xv * wxb[      hc] + bbl[      hc];
    float zi = zbuf[r * 128 +  32 + hc] + xv * wxb[ 32 + hc] + bbl[ 32 + hc];
    float zf = zbuf[r * 128 +  64 + hc] + xv * wxb[ 64 + hc] + bbl[ 64 + hc];
    float zo = zbuf[r * 128 +  96 + hc] + xv * wxb[ 96 + hc] + bbl[ 96 + hc];
    float G = tanhf_(zg), I = sigmf_(zi), F = sigmf_(zf), O = sigmf_(zo);
    float cold = e ? creg1 : creg0;
    float cnew = G * I + cold * F;
    if (e) creg1 = cnew; else creg0 = cnew;
    hW[(size_t)(r0 + r) * Hd + hc0 + hc] = f2bf(tanhf_(cnew) * O);
  }

  cbuf[ci_a] = creg0;
  cbuf[ci_b] = creg1;
}

// ---- projection + softmax ----
__global__ __launch_bounds__(256) void lstm_final(
    const unsigned short* __restrict__ h, const float* __restrict__ wph,
    const float* __restrict__ bp, float* __restrict__ out)
{
  __shared__ float zrow[16][10];
  const int tid = threadIdx.x;
  if (tid < 160) {
    int rr = tid / 10, c = tid - rr * 10;
    int r = blockIdx.x * 16 + rr;
    float acc = bp[c];
    for (int k8 = 0; k8 < 128; ++k8) {
      bf16x8 hv = *(const bf16x8*)(h + (size_t)r * Hd + k8 * 8);
      #pragma unroll
      for (int e = 0; e < 8; ++e)
        acc += bf2f((unsigned short)hv[e]) * wph[(k8 * 8 + e) * Cc + c];
    }
    zrow[rr][c] = acc;
  }
  __syncthreads();
  if (tid < 16) {
    int r = blockIdx.x * 16 + tid;
    float m = -1e30f;
    #pragma unroll
    for (int cc = 0; cc < Cc; ++cc) m = fmaxf(m, zrow[tid][cc]);
    float s = 0.f;
    float ev[Cc];
    #pragma unroll
    for (int cc = 0; cc < Cc; ++cc) { ev[cc] = __expf(zrow[tid][cc] - m); s += ev[cc]; }
    float inv = 1.0f / s;
    #pragma unroll
    for (int cc = 0; cc < Cc; ++cc) out[r * Cc + cc] = ev[cc] * inv;
  }
}

extern "C" void kernel_launch(void* const* d_in, const int* in_sizes, int n_in,
                              void* d_out, int out_size, void* d_ws, size_t ws_size,
                              hipStream_t stream) {
  const float* x   = (const float*)d_in[0];
  const float* wgx = (const float*)d_in[1];
  const float* wgh = (const float*)d_in[2];
  const float* bg  = (const float*)d_in[3];
  const float* wix = (const float*)d_in[4];
  const float* wih = (const float*)d_in[5];
  const float* bi  = (const float*)d_in[6];
  const float* wfx = (const float*)d_in[7];
  const float* wfh = (const float*)d_in[8];
  const float* bfp = (const float*)d_in[9];
  const float* wox = (const float*)d_in[10];
  const float* woh = (const float*)d_in[11];
  const float* bo  = (const float*)d_in[12];
  const float* wph = (const float*)d_in[13];
  const float* bp  = (const float*)d_in[14];
  float* out = (float*)d_out;

  // d_ws: whT 8MB | hbuf 2x512KB | cbuf 1MB | sync (flags 4KB + cnt)
  unsigned short* whT  = (unsigned short*)d_ws;
  unsigned short* hbuf = (unsigned short*)((char*)d_ws + (size_t)4 * 1024 * Hd * 2);
  float* cbuf = (float*)((char*)hbuf + (size_t)2 * HBHALF * 2);
  unsigned* sync = (unsigned*)((char*)cbuf + (size_t)HBHALF * 4);

  hipMemsetAsync(hbuf, 0, (size_t)HBHALF * 2, stream);   // h_0 = 0
  hipMemsetAsync(cbuf, 0, (size_t)HBHALF * 4, stream);   // c_0 = 0
  hipMemsetAsync(sync, 0, (8 * 32 * 32 + 8) * sizeof(unsigned), stream);

  size_t shmem = 65536 + 16384 + (64 + 128 + 128) * sizeof(float);  // 83.2KB
  hipFuncSetAttribute((const void*)lstm_pair,
                      hipFuncAttributeMaxDynamicSharedMemorySize, (int)shmem);

  lstm_prep<<<1024, 256, 0, stream>>>(wgh, wih, wfh, woh, whT);

  for (int k = 0; k < Tt / 2; ++k) {
    lstm_pair<<<256, THREADS, shmem, stream>>>(whT, x, wgx, wix, wfx, wox,
                                               bg, bi, bfp, bo, hbuf, cbuf,
                                               sync, k);
  }

  lstm_final<<<16, 256, 0, stream>>>(hbuf /* parity 0 = h_T */, wph, bp, out);
}

// Round 14
// 6296.947 us; speedup vs baseline: 1.5722x; 1.5722x over previous
//
#include <hip/hip_runtime.h>

#define Tt  512
#define Hd  1024
#define Cc  10
#define HBHALF (256 * 1024)   // elements per h buffer [256][1024]

typedef short bf16x8 __attribute__((ext_vector_type(8)));
typedef float f32x4 __attribute__((ext_vector_type(4)));

__device__ __forceinline__ unsigned short f2bf(float f) {
  unsigned u = __builtin_bit_cast(unsigned, f);
  u = (u + 0x7FFFu + ((u >> 16) & 1u)) >> 16;   // RTNE
  return (unsigned short)u;
}
__device__ __forceinline__ float bf2f(unsigned short s) {
  unsigned u = ((unsigned)s) << 16;
  return __builtin_bit_cast(float, u);
}
__device__ __forceinline__ float sigmf_(float z) { return 1.0f / (1.0f + __expf(-z)); }
__device__ __forceinline__ float tanhf_(float z) { return 1.0f - 2.0f / (__expf(2.0f * z) + 1.0f); }

// ---- prep: fuse+transpose Wh (f32 [k][col]) -> whT (bf16 [gate][col][k]) ----
__global__ __launch_bounds__(256) void lstm_prep(
    const float* __restrict__ wgh, const float* __restrict__ wih,
    const float* __restrict__ wfh, const float* __restrict__ woh,
    unsigned short* __restrict__ whT)
{
  __shared__ float tile[64][65];
  const int bid = blockIdx.x;
  const int q  = bid >> 8;
  const int ct = (bid >> 4) & 15;
  const int kt = bid & 15;
  const float* w = (q == 0) ? wgh : (q == 1) ? wih : (q == 2) ? wfh : woh;
  const int tid = threadIdx.x;
  const int tc = tid & 63, tr = tid >> 6;
  #pragma unroll
  for (int i = 0; i < 16; ++i) {
    int kk = i * 4 + tr;
    tile[kk][tc] = w[(size_t)(kt * 64 + kk) * Hd + ct * 64 + tc];
  }
  __syncthreads();
  #pragma unroll
  for (int i = 0; i < 16; ++i) {
    int cc = i * 4 + tr;
    whT[(size_t)(q * 1024 + ct * 64 + cc) * Hd + kt * 64 + tc] = f2bf(tile[tc][cc]);
  }
}

// ---- one timestep: block = 64 rows x 32 h-cols (128 z-cols), 128 blocks ----
// Each wave's B-fragment feeds 4 row-tiles -> half the weight re-reads of v9.
// XCD locality: blockIdx%8 = cb%8 -> 1MB distinct weights per XCD (L2-resident).
__global__ __launch_bounds__(512) void lstm_step(
    const unsigned short* __restrict__ whT,
    const float* __restrict__ x,
    const float* __restrict__ wgx, const float* __restrict__ wix,
    const float* __restrict__ wfx, const float* __restrict__ wox,
    const float* __restrict__ bg,  const float* __restrict__ bi,
    const float* __restrict__ bfp, const float* __restrict__ bo,
    const unsigned short* __restrict__ hR,   // h_t   [256][1024] bf16
    unsigned short* __restrict__ hW,         // h_t+1 [256][1024] bf16
    float* __restrict__ cbuf,                // c     [256][1024] f32
    int t)
{
  extern __shared__ char smem[];             // 128KB
  char*  hls  = smem;                        // [64 rows][2048B] swizzled bf16
  float* zbuf = (float*)smem;                // [64][128] f32 (reuses hls after barrier)
  __shared__ float xsh[64];

  const int tid = threadIdx.x;
  const int l   = tid & 63;
  const int w   = tid >> 6;        // wave 0..7
  const int rg  = blockIdx.x >> 5; // row group 0..3
  const int cb  = blockIdx.x & 31; // col block 0..31
  const int r0  = rg * 64;
  const int hc0 = cb * 32;

  if (tid < 64) xsh[tid] = x[(size_t)(r0 + tid) * Tt + t];

  // ---- stage h rows [r0, r0+64) -> LDS (pre-swizzled global source) ----
  {
    int rbase = w * 8;
    #pragma unroll
    for (int i = 0; i < 16; ++i) {
      int r = rbase + (i >> 1);
      int half = i & 1;
      char* ldsb = hls + r * 2048 + half * 1024;    // wave-uniform, linear dest
      int m = half * 64 + l;                         // dest 16B-chunk index
      int srcc = m ^ (r & 7);                        // inverse swizzle on source
      const char* gp = (const char*)hR + ((size_t)(r0 + r) << 11) + srcc * 16;
      __builtin_amdgcn_global_load_lds(gp, ldsb, 16, 0, 0);
    }
  }
  __syncthreads();

  // ---- z-tile: wave w -> gate q = w>>1, col-half w&1; 4 row-tiles share B ----
  const int q  = w >> 1;
  const int lc = l & 15;
  const int swz   = (l & 7) << 4;
  const int kboff = (l >> 4) * 16;           // byte offset of k sub-chunk
  const unsigned short* wcol =
      whT + (size_t)(q * 1024 + hc0 + ((w & 1) << 4) + lc) * Hd + (l >> 4) * 8;

  f32x4 acc0 = {0.f,0.f,0.f,0.f};
  f32x4 acc1 = {0.f,0.f,0.f,0.f};
  f32x4 acc2 = {0.f,0.f,0.f,0.f};
  f32x4 acc3 = {0.f,0.f,0.f,0.f};
  const int roff = lc * 2048;
  #pragma unroll
  for (int kc = 0; kc < 32; ++kc) {
    int boff = (kc * 64 + kboff) ^ swz;
    bf16x8 b  = *(const bf16x8*)(wcol + kc * 32);
    bf16x8 a0 = *(const bf16x8*)(hls + roff + boff);
    bf16x8 a1 = *(const bf16x8*)(hls + roff + 16 * 2048 + boff);
    bf16x8 a2 = *(const bf16x8*)(hls + roff + 32 * 2048 + boff);
    bf16x8 a3 = *(const bf16x8*)(hls + roff + 48 * 2048 + boff);
    acc0 = __builtin_amdgcn_mfma_f32_16x16x32_bf16(a0, b, acc0, 0, 0, 0);
    acc1 = __builtin_amdgcn_mfma_f32_16x16x32_bf16(a1, b, acc1, 0, 0, 0);
    acc2 = __builtin_amdgcn_mfma_f32_16x16x32_bf16(a2, b, acc2, 0, 0, 0);
    acc3 = __builtin_amdgcn_mfma_f32_16x16x32_bf16(a3, b, acc3, 0, 0, 0);
  }
  __syncthreads();                 // all A reads done -> hls reusable as zbuf

  // ---- acc -> zbuf (C/D layout: col = l&15, row = (l>>4)*4 + p + 16*tile) ----
  {
    int colz = (w << 4) + lc;      // fused z-col: q*32 + (w&1)*16 + lc
    int rb   = (l >> 4) * 4;
    #pragma unroll
    for (int p = 0; p < 4; ++p) {
      zbuf[(rb + p) * 128 + colz]      = acc0[p];
      zbuf[(rb + p + 16) * 128 + colz] = acc1[p];
      zbuf[(rb + p + 32) * 128 + colz] = acc2[p];
      zbuf[(rb + p + 48) * 128 + colz] = acc3[p];
    }
  }
  __syncthreads();

  // ---- gates + c update (f32), write h' and c: 64 rows x 32 h-cols ----
  #pragma unroll
  for (int e = 0; e < 4; ++e) {
    int idx = tid + e * 512;
    int r = idx >> 5, hc = idx & 31;
    int hcol = hc0 + hc;
    float xv = xsh[r];
    float zg = zbuf[r * 128 +       hc] + xv * wgx[hcol] + bg[hcol];
    float zi = zbuf[r * 128 +  32 + hc] + xv * wix[hcol] + bi[hcol];
    float zf = zbuf[r * 128 +  64 + hc] + xv * wfx[hcol] + bfp[hcol];
    float zo = zbuf[r * 128 +  96 + hc] + xv * wox[hcol] + bo[hcol];
    float G = tanhf_(zg);
    float I = sigmf_(zi);
    float F = sigmf_(zf);
    float O = sigmf_(zo);
    size_t ci = (size_t)(r0 + r) * Hd + hcol;
    float cnew = G * I + cbuf[ci] * F;
    cbuf[ci] = cnew;
    hW[ci] = f2bf(tanhf_(cnew) * O);
  }
}

// ---- projection + softmax ----
__global__ __launch_bounds__(256) void lstm_final(
    const unsigned short* __restrict__ h, const float* __restrict__ wph,
    const float* __restrict__ bp, float* __restrict__ out)
{
  __shared__ float zrow[16][10];
  const int tid = threadIdx.x;
  if (tid < 160) {
    int rr = tid / 10, c = tid - rr * 10;
    int r = blockIdx.x * 16 + rr;
    float acc = bp[c];
    for (int k8 = 0; k8 < 128; ++k8) {
      bf16x8 hv = *(const bf16x8*)(h + (size_t)r * Hd + k8 * 8);
      #pragma unroll
      for (int e = 0; e < 8; ++e)
        acc += bf2f((unsigned short)hv[e]) * wph[(k8 * 8 + e) * Cc + c];
    }
    zrow[rr][c] = acc;
  }
  __syncthreads();
  if (tid < 16) {
    int r = blockIdx.x * 16 + tid;
    float m = -1e30f;
    #pragma unroll
    for (int cc = 0; cc < Cc; ++cc) m = fmaxf(m, zrow[tid][cc]);
    float s = 0.f;
    float ev[Cc];
    #pragma unroll
    for (int cc = 0; cc < Cc; ++cc) { ev[cc] = __expf(zrow[tid][cc] - m); s += ev[cc]; }
    float inv = 1.0f / s;
    #pragma unroll
    for (int cc = 0; cc < Cc; ++cc) out[r * Cc + cc] = ev[cc] * inv;
  }
}

extern "C" void kernel_launch(void* const* d_in, const int* in_sizes, int n_in,
                              void* d_out, int out_size, void* d_ws, size_t ws_size,
                              hipStream_t stream) {
  const float* x   = (const float*)d_in[0];
  const float* wgx = (const float*)d_in[1];
  const float* wgh = (const float*)d_in[2];
  const float* bg  = (const float*)d_in[3];
  const float* wix = (const float*)d_in[4];
  const float* wih = (const float*)d_in[5];
  const float* bi  = (const float*)d_in[6];
  const float* wfx = (const float*)d_in[7];
  const float* wfh = (const float*)d_in[8];
  const float* bfp = (const float*)d_in[9];
  const float* wox = (const float*)d_in[10];
  const float* woh = (const float*)d_in[11];
  const float* bo  = (const float*)d_in[12];
  const float* wph = (const float*)d_in[13];
  const float* bp  = (const float*)d_in[14];
  float* out = (float*)d_out;

  // d_ws layout: whT 8.0MB | hbuf 2x512KB | cbuf 1MB
  unsigned short* whT  = (unsigned short*)d_ws;
  unsigned short* hbuf = (unsigned short*)((char*)d_ws + (size_t)4 * 1024 * Hd * 2);
  float* cbuf = (float*)((char*)hbuf + (size_t)2 * HBHALF * 2);

  hipMemsetAsync(hbuf, 0, (size_t)HBHALF * 2, stream);       // h_0 = 0
  hipMemsetAsync(cbuf, 0, (size_t)HBHALF * 4, stream);       // c_0 = 0

  size_t shmem = 131072;   // 128KB dynamic (+ static xsh)
  hipFuncSetAttribute((const void*)lstm_step,
                      hipFuncAttributeMaxDynamicSharedMemorySize, (int)shmem);

  lstm_prep<<<1024, 256, 0, stream>>>(wgh, wih, wfh, woh, whT);

  for (int t = 0; t < Tt; ++t) {
    const unsigned short* hR = hbuf + (size_t)(t & 1) * HBHALF;
    unsigned short*       hW = hbuf + (size_t)((t + 1) & 1) * HBHALF;
    lstm_step<<<128, 512, shmem, stream>>>(whT, x, wgx, wix, wfx, wox,
                                           bg, bi, bfp, bo, hR, hW, cbuf, t);
  }

  lstm_final<<<16, 256, 0, stream>>>(hbuf /* parity 0 = h_T */, wph, bp, out);
}